// Round 2
// baseline (785.306 us; speedup 1.0000x reference)
//
#include <hip/hip_runtime.h>

#define EPS 1e-10f
#define HALF_LN2PI 0.91893853320467274f

// problem constants: b=16, win=14, w=6, ww=36, B_T=32, K=3, Bkk=288, C_T=32, HH=16
//
// Reference quirk: poses_r = patches.reshape(b,B_T,K,K,1,w,w,H,H) regroups the
// trailing (HH=16, ww=36) dims (flat f = h*36 + s) as (1,6,6,4,4), so the pose
// "matrix" fed to the matmul at output position p=(q1*6+q2) is
//   M[m][hc] = patchflat[ base(p) + m*4 + hc ],  base(p) = (p/6)*96 + (p%6)*16
// i.e. a contiguous 16-float slice of the flat (h,s) patch array, NOT the
// (h = m*4+hc, s = p) decomposition.

__global__ void precompute_patches(const float* __restrict__ poses,
                                   const float* __restrict__ acts,
                                   float* __restrict__ Pt, float* __restrict__ actp)
{
    const int blk = blockIdx.x;            // bb*36 + p
    const int bb = blk / 36, p = blk % 36;
    const int base = (p / 6) * 96 + (p % 6) * 16;
    const size_t pbase = (size_t)blk * (288 * 16);
    // Pt stored transposed for float4 vote loads: Pt[i][hc*4+m] = patchflat[base + m*4 + hc]
    for (int e = threadIdx.x; e < 288 * 16; e += 256) {
        int i = e >> 4, j = e & 15;
        int hc = j >> 2, m = j & 3;
        int f = base + m * 4 + hc;         // flat (h,s) index
        int h = f / 36, sp = f % 36;
        int y = sp / 6, x = sp % 6;        // s = y*6 + x
        int B = i / 9, kk = i % 9;
        int ki = kk / 3, kj = kk % 3;
        int r = 2 * x + ki, cc = 2 * y + kj;
        Pt[pbase + e] = poses[(size_t)((bb * 512 + h * 32 + B) * 14 + r) * 14 + cc];
    }
    // activation patch at position p: s = p, y = p/6, x = p%6
    {
        const int y = p / 6, x = p % 6;
        for (int e = threadIdx.x; e < 288; e += 256) {
            int B = e / 9, kk = e % 9;
            int ki = kk / 3, kj = kk % 3;
            int r = 2 * x + ki, cc = 2 * y + kj;
            actp[(size_t)blk * 288 + e] = acts[(size_t)((bb * 32 + B) * 14 + r) * 14 + cc];
        }
    }
}

template <int ITER>
__global__ __launch_bounds__(512)
void em_iter(const float* __restrict__ Pt, const float* __restrict__ actp,
             const float* __restrict__ W, const float* __restrict__ beta_v,
             const float* __restrict__ beta_a, const float* __restrict__ lambda_p,
             float* __restrict__ ap_buf, const float* __restrict__ denom_prev,
             float* __restrict__ denom_next, float* __restrict__ d_out)
{
    __shared__ __align__(16) float W_lds[4608];   // W[B] slice: 9*32*16
    __shared__ __align__(16) float Pt_lds[4608];  // patches: 288*16 (transposed)
    __shared__ float act_lds[288];
    __shared__ float invd_lds[288];
    __shared__ float red_lds[288];

    const int tid = threadIdx.x;
    const int c = tid >> 4;        // output capsule type 0..31
    const int h = tid & 15;        // output HH element = hr*4 + hc
    const int hr = h >> 2, hc = h & 3;
    const int blk = blockIdx.x;
    const int bb = blk / 36;

    const size_t pbase = (size_t)blk * 4608;
    const size_t apbase = (size_t)blk * (288 * 32);

    for (int e = tid; e < 4608; e += 512) Pt_lds[e] = Pt[pbase + e];
    for (int e = tid; e < 288; e += 512) act_lds[e] = actp[(size_t)blk * 288 + e];
    if (ITER > 0) {
        for (int e = tid; e < 288; e += 512)
            invd_lds[e] = 1.0f / (denom_prev[bb * 288 + e] + EPS);
    }

    // ---------------- M step: one pass over i, three moments ----------------
    float S1 = 0.f, S2 = 0.f, sumR = 0.f;
    for (int B = 0; B < 32; ++B) {
        __syncthreads();
        for (int e = tid; e < 4608; e += 512) W_lds[e] = W[B * 4608 + e];
        __syncthreads();
#pragma unroll
        for (int kk = 0; kk < 9; ++kk) {
            int i = B * 9 + kk;
            float R;
            if (ITER == 0) R = 1.0f / 32.0f;
            else R = ap_buf[apbase + i * 32 + c] * invd_lds[i] + EPS;
            float R4 = R * act_lds[i];
            const float4 wv = *reinterpret_cast<const float4*>(&W_lds[kk * 512 + c * 16 + hr * 4]);
            const float4 pv = *reinterpret_cast<const float4*>(&Pt_lds[i * 16 + hc * 4]);
            float V = wv.x * pv.x + wv.y * pv.y + wv.z * pv.z + wv.w * pv.w;
            S1 = fmaf(R4, V, S1);
            S2 = fmaf(R4 * V, V, S2);
            sumR += R4;
        }
    }

    float mu = S1 / sumR;
    float ss = S2 / sumR - mu * mu;
    ss = fmaxf(ss, 1e-30f);
    float logt = __logf(sqrtf(ss) + EPS);           // log(sqrt(ss)+EPS) for cost
    float sl = logt;
    sl += __shfl_xor(sl, 1);
    sl += __shfl_xor(sl, 2);
    sl += __shfl_xor(sl, 4);
    sl += __shfl_xor(sl, 8);
    float costsum = sumR * (16.0f * beta_v[c] + sl);
    float lam = lambda_p[0];
    float xarg = lam * (beta_a[c] - costsum);
    float a_c = 1.0f / (1.0f + __expf(-xarg));

    if (ITER < 2) {
        // ---------------- E step: recompute V, p, ap; accumulate denom ----------------
        float halflog = 0.5f * __logf(ss);          // log(sqrt(ss)) — no EPS here (matches ref)
        float inv2ss = 0.5f / ss;
        for (int B = 0; B < 32; ++B) {
            __syncthreads();
            for (int e = tid; e < 4608; e += 512) W_lds[e] = W[B * 4608 + e];
            __syncthreads();
#pragma unroll
            for (int kk = 0; kk < 9; ++kk) {
                int i = B * 9 + kk;
                const float4 wv = *reinterpret_cast<const float4*>(&W_lds[kk * 512 + c * 16 + hr * 4]);
                const float4 pv = *reinterpret_cast<const float4*>(&Pt_lds[i * 16 + hc * 4]);
                float V = wv.x * pv.x + wv.y * pv.y + wv.z * pv.z + wv.w * pv.w;
                float d = V - mu;
                float lnp = -(d * d) * inv2ss - halflog - HALF_LN2PI;
                float pe = __expf(lnp);
                pe += __shfl_xor(pe, 1);
                pe += __shfl_xor(pe, 2);
                pe += __shfl_xor(pe, 4);
                pe += __shfl_xor(pe, 8);
                if (h == 0) red_lds[kk * 32 + c] = a_c * pe;   // ap for (i, c)
            }
            __syncthreads();
            if (tid < 288) {
                float apv = red_lds[tid];                       // tid = kk*32 + c
                ap_buf[apbase + B * 288 + tid] = apv;           // = apbase + i*32 + c
                float dsum = apv;
                dsum += __shfl_xor(dsum, 1);
                dsum += __shfl_xor(dsum, 2);
                dsum += __shfl_xor(dsum, 4);
                dsum += __shfl_xor(dsum, 8);
                dsum += __shfl_xor(dsum, 16);
                if ((tid & 31) == 0)
                    atomicAdd(&denom_next[bb * 288 + B * 9 + (tid >> 5)], dsum);
            }
        }
    } else {
        // ---------------- final: write mu and a in reference flat layout ----------------
        // mu: (b, C_T, w, w, HH) flat = bb*18432 + (c*36+p)*16 + h
        const int p = blk % 36;
        d_out[(size_t)bb * 18432 + (size_t)(c * 36 + p) * 16 + h] = mu;
        if (h == 0)
            d_out[294912 + (size_t)bb * 1152 + c * 36 + p] = a_c;
    }
}

extern "C" void kernel_launch(void* const* d_in, const int* in_sizes, int n_in,
                              void* d_out, int out_size, void* d_ws, size_t ws_size,
                              hipStream_t stream)
{
    const float* lambda_p = (const float*)d_in[0];
    const float* poses    = (const float*)d_in[1];
    const float* acts     = (const float*)d_in[2];
    const float* W        = (const float*)d_in[3];
    const float* beta_v   = (const float*)d_in[4];
    const float* beta_a   = (const float*)d_in[5];
    float* out = (float*)d_out;

    float* ws     = (float*)d_ws;
    float* Pt     = ws;                     // 16*36*288*16 = 2,654,208 floats
    float* actp   = Pt + 2654208;           // 16*36*288    =   165,888
    float* ap_buf = actp + 165888;          // 16*36*288*32 = 5,308,416
    float* denom0 = ap_buf + 5308416;       // 16*288 = 4608
    float* denom1 = denom0 + 4608;          // 4608

    hipMemsetAsync(denom0, 0, 2 * 4608 * sizeof(float), stream);
    precompute_patches<<<576, 256, 0, stream>>>(poses, acts, Pt, actp);
    em_iter<0><<<576, 512, 0, stream>>>(Pt, actp, W, beta_v, beta_a, lambda_p,
                                        ap_buf, nullptr, denom0, out);
    em_iter<1><<<576, 512, 0, stream>>>(Pt, actp, W, beta_v, beta_a, lambda_p,
                                        ap_buf, denom0, denom1, out);
    em_iter<2><<<576, 512, 0, stream>>>(Pt, actp, W, beta_v, beta_a, lambda_p,
                                        ap_buf, denom1, nullptr, out);
}

// Round 3
// 196.680 us; speedup vs baseline: 3.9928x; 3.9928x over previous
//
#include <hip/hip_runtime.h>

#define EPS 1e-10f
#define HALF_LN2PI 0.91893853320467274f

// b=16, win=14, w=6, ww=36, B_T=32, K=3, Bkk=288 (=i), C_T=32, HH=16
//
// W flat: [i=288][c=32][hr=4][m=4]  -> elem = i*512 + c*16 + hr*4 + m
// Pt per block: [i=288][hc=4][m=4]:  Pt[i*16 + hc*4 + m] = patchflat[base(p) + m*4 + hc]
//   where base(p) = (p/6)*96 + (p%6)*16   (the reference's reshape quirk)
//
// Thread map: wave = tid>>6 (i-slice, 36 i's each), lane = cl*4 + hr,
// each thread computes c in {cl, cl+16}, 4 hc values per c.

template <int ITER>
__global__ __launch_bounds__(512)
void em_iter(const float* __restrict__ poses, const float* __restrict__ acts,
             float* __restrict__ Ptg, float* __restrict__ actp,
             const float* __restrict__ W, const float* __restrict__ beta_v,
             const float* __restrict__ beta_a, const float* __restrict__ lambda_p,
             float* __restrict__ ap_buf, const float* __restrict__ denom_prev,
             float* __restrict__ denom_next, float* __restrict__ d_out)
{
    __shared__ __align__(16) float Pt_lds[4608];
    __shared__ float act_lds[288];
    __shared__ float invd_lds[288];
    __shared__ __align__(16) float red[256 * 19];          // reduction tree (19.5 KB)
    __shared__ float mu_lds[512], n2s_lds[512], hl_lds[512];
    __shared__ float a_lds[32];

    const int tid  = threadIdx.x;
    const int wave = tid >> 6;          // i-slice 0..7
    const int lane = tid & 63;
    const int cl   = lane >> 2;         // 0..15; c pair {cl, cl+16}
    const int hr   = lane & 3;
    const int blk  = blockIdx.x;
    const int bb   = blk / 36, p = blk % 36;
    const int i0   = wave * 36;

    const size_t pbase  = (size_t)blk * 4608;
    const size_t apbase = (size_t)blk * 9216;

    // ---------------- stage patches (+ gather on ITER 0) ----------------
    if (ITER == 0) {
        const int base = (p / 6) * 96 + (p % 6) * 16;
        for (int e = tid; e < 4608; e += 512) {
            int i = e >> 4, j = e & 15;
            int hc = j >> 2, m = j & 3;
            int f = base + m * 4 + hc;              // flat (h,s) index
            int h = f / 36, sp = f - h * 36;
            int y = sp / 6, x = sp - y * 6;
            int B = i / 9, kk = i - B * 9;
            int ki = kk / 3, kj = kk - ki * 3;
            float v = poses[(size_t)((bb * 512 + h * 32 + B) * 14 + 2 * x + ki) * 14 + 2 * y + kj];
            Pt_lds[e] = v;
            Ptg[pbase + e] = v;
        }
        const int y = p / 6, x = p - y * 6;
        for (int e = tid; e < 288; e += 512) {
            int B = e / 9, kk = e - B * 9;
            int ki = kk / 3, kj = kk - ki * 3;
            float v = acts[(size_t)((bb * 32 + B) * 14 + 2 * x + ki) * 14 + 2 * y + kj];
            act_lds[e] = v;
            actp[blk * 288 + e] = v;
        }
    } else {
        const float4* Pg4 = (const float4*)(Ptg + pbase);
        float4* Pl4 = (float4*)Pt_lds;
        for (int e = tid; e < 1152; e += 512) Pl4[e] = Pg4[e];
        for (int e = tid; e < 288; e += 512) act_lds[e] = actp[blk * 288 + e];
        for (int e = tid; e < 288; e += 512)
            invd_lds[e] = 1.0f / (denom_prev[bb * 288 + e] + EPS);
    }
    __syncthreads();

    // ---------------- M step: barrier-free pass over this wave's 36 i ----------------
    // acc: [0..3]=S1a [4..7]=S2a [8..11]=S1b [12..15]=S2b [16]=sRa [17]=sRb
    float acc[18];
#pragma unroll
    for (int k = 0; k < 18; ++k) acc[k] = 0.f;

    const float* Wt = W + (size_t)i0 * 512 + (lane << 2);
#pragma unroll 2
    for (int t = 0; t < 36; ++t) {
        const int i = i0 + t;
        const float4 wva = *(const float4*)(Wt + (size_t)t * 512);
        const float4 wvb = *(const float4*)(Wt + (size_t)t * 512 + 256);
        float Ra, Rb;
        if (ITER == 0) {
            Ra = 1.0f / 32.0f; Rb = 1.0f / 32.0f;
        } else {
            float inv = invd_lds[i];
            Ra = fmaf(ap_buf[apbase + i * 32 + cl], inv, EPS);
            Rb = fmaf(ap_buf[apbase + i * 32 + cl + 16], inv, EPS);
        }
        const float a_in = act_lds[i];
        const float R4a = Ra * a_in, R4b = Rb * a_in;
        acc[16] += R4a; acc[17] += R4b;
#pragma unroll
        for (int hc = 0; hc < 4; ++hc) {
            const float4 pv = *(const float4*)&Pt_lds[i * 16 + hc * 4];
            float Va = wva.x * pv.x + wva.y * pv.y + wva.z * pv.z + wva.w * pv.w;
            float Vb = wvb.x * pv.x + wvb.y * pv.y + wvb.z * pv.z + wvb.w * pv.w;
            acc[hc]      = fmaf(R4a, Va, acc[hc]);
            acc[4 + hc]  = fmaf(R4a * Va, Va, acc[4 + hc]);
            acc[8 + hc]  = fmaf(R4b, Vb, acc[8 + hc]);
            acc[12 + hc] = fmaf(R4b * Vb, Vb, acc[12 + hc]);
        }
    }

    // ---------------- cross-wave tree reduce (3 rounds, 6 barriers) ----------------
#pragma unroll
    for (int half = 4; half >= 1; half >>= 1) {
        if (wave >= half && wave < 2 * half) {
            float* dst = &red[((wave - half) * 64 + lane) * 19];
#pragma unroll
            for (int k = 0; k < 18; ++k) dst[k] = acc[k];
        }
        __syncthreads();
        if (wave < half) {
            const float* src = &red[(wave * 64 + lane) * 19];
#pragma unroll
            for (int k = 0; k < 18; ++k) acc[k] += src[k];
        }
        __syncthreads();
    }

    // ---------------- stats on wave 0 ----------------
    if (wave == 0) {
        const float lam = lambda_p[0];
#pragma unroll
        for (int q = 0; q < 2; ++q) {
            const int c = cl + q * 16;
            const float sR = acc[16 + q];
            float ls = 0.f;
#pragma unroll
            for (int hc = 0; hc < 4; ++hc) {
                const float S1 = acc[q * 8 + hc];
                const float S2 = acc[q * 8 + 4 + hc];
                const float mu = S1 / sR;
                float ss = S2 / sR - mu * mu;
                ss = fmaxf(ss, 1e-30f);
                if (ITER < 2) {
                    mu_lds[lane * 4 + q * 256 + hc]  = mu;
                    n2s_lds[lane * 4 + q * 256 + hc] = -0.5f / ss;
                    hl_lds[lane * 4 + q * 256 + hc]  = -0.5f * __logf(ss) - HALF_LN2PI;
                } else {
                    d_out[(size_t)bb * 18432 + (size_t)(c * 36 + p) * 16 + hr * 4 + hc] = mu;
                }
                ls += __logf(sqrtf(ss) + EPS);
            }
            ls += __shfl_xor(ls, 1);
            ls += __shfl_xor(ls, 2);
            const float cost = sR * (16.0f * beta_v[c] + ls);
            const float av = 1.0f / (1.0f + __expf(-lam * (beta_a[c] - cost)));
            if (ITER < 2) {
                if (hr == 0) a_lds[c] = av;
            } else {
                if (hr == 0) d_out[294912 + (size_t)bb * 1152 + c * 36 + p] = av;
            }
        }
    }
    __syncthreads();

    // ---------------- E step (ITER 0,1): barrier-free ----------------
    if (ITER < 2) {
        const float aca = a_lds[cl], acb = a_lds[cl + 16];
        __align__(16) float mua[4], mub[4], na[4], nb[4], ha[4], hb[4];
        *(float4*)mua = *(const float4*)&mu_lds[lane * 4];
        *(float4*)mub = *(const float4*)&mu_lds[lane * 4 + 256];
        *(float4*)na  = *(const float4*)&n2s_lds[lane * 4];
        *(float4*)nb  = *(const float4*)&n2s_lds[lane * 4 + 256];
        *(float4*)ha  = *(const float4*)&hl_lds[lane * 4];
        *(float4*)hb  = *(const float4*)&hl_lds[lane * 4 + 256];

#pragma unroll 2
        for (int t = 0; t < 36; ++t) {
            const int i = i0 + t;
            const float4 wva = *(const float4*)(Wt + (size_t)t * 512);
            const float4 wvb = *(const float4*)(Wt + (size_t)t * 512 + 256);
            float pea = 0.f, peb = 0.f;
#pragma unroll
            for (int hc = 0; hc < 4; ++hc) {
                const float4 pv = *(const float4*)&Pt_lds[i * 16 + hc * 4];
                float Va = wva.x * pv.x + wva.y * pv.y + wva.z * pv.z + wva.w * pv.w;
                float Vb = wvb.x * pv.x + wvb.y * pv.y + wvb.z * pv.z + wvb.w * pv.w;
                float da = Va - mua[hc];
                float db = Vb - mub[hc];
                pea += __expf(fmaf(da * da, na[hc], ha[hc]));
                peb += __expf(fmaf(db * db, nb[hc], hb[hc]));
            }
            pea += __shfl_xor(pea, 1);
            pea += __shfl_xor(pea, 2);
            peb += __shfl_xor(peb, 1);
            peb += __shfl_xor(peb, 2);
            const float apa = aca * pea;
            const float apb = acb * peb;
            if (hr == 0) {
                ap_buf[apbase + i * 32 + cl]      = apa;
                ap_buf[apbase + i * 32 + cl + 16] = apb;
            }
            float dsum = apa + apb;
            dsum += __shfl_xor(dsum, 4);
            dsum += __shfl_xor(dsum, 8);
            dsum += __shfl_xor(dsum, 16);
            dsum += __shfl_xor(dsum, 32);
            if (lane == 0)
                atomicAdd(&denom_next[bb * 288 + i], dsum);
        }
    }
}

extern "C" void kernel_launch(void* const* d_in, const int* in_sizes, int n_in,
                              void* d_out, int out_size, void* d_ws, size_t ws_size,
                              hipStream_t stream)
{
    const float* lambda_p = (const float*)d_in[0];
    const float* poses    = (const float*)d_in[1];
    const float* acts     = (const float*)d_in[2];
    const float* W        = (const float*)d_in[3];
    const float* beta_v   = (const float*)d_in[4];
    const float* beta_a   = (const float*)d_in[5];
    float* out = (float*)d_out;

    float* ws     = (float*)d_ws;
    float* Ptg    = ws;                     // 576*4608 = 2,654,208 floats
    float* actp   = Ptg + 2654208;          // 576*288  =   165,888
    float* ap_buf = actp + 165888;          // 576*9216 = 5,308,416
    float* denom0 = ap_buf + 5308416;       // 4608
    float* denom1 = denom0 + 4608;          // 4608

    hipMemsetAsync(denom0, 0, 2 * 4608 * sizeof(float), stream);
    em_iter<0><<<576, 512, 0, stream>>>(poses, acts, Ptg, actp, W, beta_v, beta_a,
                                        lambda_p, ap_buf, denom1, denom0, out);
    em_iter<1><<<576, 512, 0, stream>>>(poses, acts, Ptg, actp, W, beta_v, beta_a,
                                        lambda_p, ap_buf, denom0, denom1, out);
    em_iter<2><<<576, 512, 0, stream>>>(poses, acts, Ptg, actp, W, beta_v, beta_a,
                                        lambda_p, ap_buf, denom1, denom0, out);
}

// Round 4
// 190.664 us; speedup vs baseline: 4.1188x; 1.0316x over previous
//
#include <hip/hip_runtime.h>

#define EPS 1e-10f
#define HALF_LN2PI 0.91893853320467274f

// b=16, win=14, w=6, ww=36, B_T=32, K=3, Bkk=288 (=i), C_T=32, HH=16
//
// W flat: [i=288][c=32][hr=4][m=4]  -> elem = i*512 + c*16 + hr*4 + m
// Pt per (bb,p) tile: [i=288][hc=4][m=4]: Pt[i*16+hc*4+m] = patchflat[base(p)+m*4+hc]
//   base(p) = (p/6)*96 + (p%6)*16   (reference reshape quirk: (HH,ww) flat regrouped)
//
// Grid: 2304 blocks = (blk = bb*36+p) * 4 i-quarters; 256 threads = 4 waves.
// Wave handles 18 i's; lane = cl*4+hr; each thread covers c in {cl, cl+16}.
// Moments: per-block partials -> Mpart[bid][k*64+lane] (k=0..17), summed in E/Sout.
// acc map: [0..3]=S1a(hc) [4..7]=S2a [8..11]=S1b [12..15]=S2b [16]=sRa [17]=sRb

template <int IT>
__global__ __launch_bounds__(256)
void m_pass(const float* __restrict__ poses, const float* __restrict__ acts,
            float* __restrict__ Ptg, float* __restrict__ actp,
            const float* __restrict__ W,
            const float* __restrict__ ap_buf, const float* __restrict__ denom_prev,
            float* __restrict__ Mpart)
{
    __shared__ __align__(16) float Pt_lds[1152];   // 72 i x 16
    __shared__ float act_lds[72];
    __shared__ float invd_lds[72];
    __shared__ __align__(16) float red[128 * 18];  // 9.2 KB tree

    const int tid  = threadIdx.x;
    const int wave = tid >> 6, lane = tid & 63;
    const int cl   = lane >> 2;
    const int bid  = blockIdx.x;
    const int blk  = bid >> 2, iq = bid & 3;
    const int bb   = blk / 36, p = blk - bb * 36;
    const int i0   = iq * 72;
    const size_t pbase  = (size_t)blk * 4608;
    const size_t apbase = (size_t)blk * 9216;

    if (IT == 0) {
        const int base = (p / 6) * 96 + (p % 6) * 16;
        for (int e = tid; e < 1152; e += 256) {
            int il = e >> 4, j = e & 15;
            int i = i0 + il;
            int hc = j >> 2, m = j & 3;
            int f = base + m * 4 + hc;              // flat (h,s)
            int h = f / 36, sp = f - h * 36;
            int y = sp / 6, x = sp - y * 6;
            int B = i / 9, kk = i - B * 9;
            int ki = kk / 3, kj = kk - ki * 3;
            float v = poses[(size_t)((bb * 512 + h * 32 + B) * 14 + 2 * x + ki) * 14 + 2 * y + kj];
            Pt_lds[e] = v;
            Ptg[pbase + (size_t)i0 * 16 + e] = v;
        }
        const int y = p / 6, x = p - y * 6;
        for (int e = tid; e < 72; e += 256) {
            int i = i0 + e;
            int B = i / 9, kk = i - B * 9;
            int ki = kk / 3, kj = kk - ki * 3;
            float v = acts[(size_t)((bb * 32 + B) * 14 + 2 * x + ki) * 14 + 2 * y + kj];
            act_lds[e] = v;
            actp[blk * 288 + i] = v;
        }
    } else {
        const float4* src = (const float4*)(Ptg + pbase + (size_t)i0 * 16);
        float4* dst = (float4*)Pt_lds;
        for (int e = tid; e < 288; e += 256) dst[e] = src[e];
        for (int e = tid; e < 72; e += 256) {
            act_lds[e]  = actp[blk * 288 + i0 + e];
            invd_lds[e] = 1.0f / (denom_prev[bb * 288 + i0 + e] + EPS);
        }
    }
    __syncthreads();

    float acc[18];
#pragma unroll
    for (int k = 0; k < 18; ++k) acc[k] = 0.f;

    const float* Wt = W + (size_t)(i0 + wave * 18) * 512 + (lane << 2);
#pragma unroll 3
    for (int t = 0; t < 18; ++t) {
        const int il = wave * 18 + t;
        const float4 wva = *(const float4*)(Wt + (size_t)t * 512);
        const float4 wvb = *(const float4*)(Wt + (size_t)t * 512 + 256);
        float Ra, Rb;
        if (IT == 0) {
            Ra = 1.0f / 32.0f; Rb = 1.0f / 32.0f;
        } else {
            const int i = i0 + il;
            const float inv = invd_lds[il];
            Ra = fmaf(ap_buf[apbase + (size_t)i * 32 + cl],      inv, EPS);
            Rb = fmaf(ap_buf[apbase + (size_t)i * 32 + cl + 16], inv, EPS);
        }
        const float a_in = act_lds[il];
        const float R4a = Ra * a_in, R4b = Rb * a_in;
        acc[16] += R4a; acc[17] += R4b;
#pragma unroll
        for (int hc = 0; hc < 4; ++hc) {
            const float4 pv = *(const float4*)&Pt_lds[il * 16 + hc * 4];
            float Va = wva.x * pv.x + wva.y * pv.y + wva.z * pv.z + wva.w * pv.w;
            float Vb = wvb.x * pv.x + wvb.y * pv.y + wvb.z * pv.z + wvb.w * pv.w;
            acc[hc]      = fmaf(R4a, Va, acc[hc]);
            acc[4 + hc]  = fmaf(R4a * Va, Va, acc[4 + hc]);
            acc[8 + hc]  = fmaf(R4b, Vb, acc[8 + hc]);
            acc[12 + hc] = fmaf(R4b * Vb, Vb, acc[12 + hc]);
        }
    }

    // 4-wave tree reduce -> wave 0
    if (wave >= 2) {
        float* d = &red[((wave - 2) * 64 + lane) * 18];
#pragma unroll
        for (int k = 0; k < 18; ++k) d[k] = acc[k];
    }
    __syncthreads();
    if (wave < 2) {
        const float* s = &red[(wave * 64 + lane) * 18];
#pragma unroll
        for (int k = 0; k < 18; ++k) acc[k] += s[k];
    }
    __syncthreads();
    if (wave == 1) {
        float* d = &red[lane * 18];
#pragma unroll
        for (int k = 0; k < 18; ++k) d[k] = acc[k];
    }
    __syncthreads();
    if (wave == 0) {
        const float* s = &red[lane * 18];
        float* mp = Mpart + (size_t)bid * 1152;
#pragma unroll
        for (int k = 0; k < 18; ++k) mp[k * 64 + lane] = acc[k] + s[k];
    }
}

__global__ __launch_bounds__(256)
void e_pass(const float* __restrict__ Ptg, const float* __restrict__ Mpart,
            const float* __restrict__ W, const float* __restrict__ beta_v,
            const float* __restrict__ beta_a, const float* __restrict__ lambda_p,
            float* __restrict__ ap_buf, float* __restrict__ denom_next)
{
    __shared__ __align__(16) float Pt_lds[1152];
    __shared__ float mu_s[512], n2_s[512], hl_s[512];
    __shared__ float a_s[32];

    const int tid  = threadIdx.x;
    const int wave = tid >> 6, lane = tid & 63;
    const int cl   = lane >> 2, hr = lane & 3;
    const int bid  = blockIdx.x;
    const int blk  = bid >> 2, iq = bid & 3;
    const int bb   = blk / 36;
    const int i0   = iq * 72;
    const size_t pbase  = (size_t)blk * 4608;
    const size_t apbase = (size_t)blk * 9216;

    {
        const float4* src = (const float4*)(Ptg + pbase + (size_t)i0 * 16);
        float4* dst = (float4*)Pt_lds;
        for (int e = tid; e < 288; e += 256) dst[e] = src[e];
    }

    if (wave == 0) {
        float s[18];
        const float* mp = Mpart + (size_t)blk * 4608;   // 4 consecutive bids
#pragma unroll
        for (int k = 0; k < 18; ++k)
            s[k] = mp[k * 64 + lane] + mp[1152 + k * 64 + lane]
                 + mp[2304 + k * 64 + lane] + mp[3456 + k * 64 + lane];
        const float lam = lambda_p[0];
#pragma unroll
        for (int q = 0; q < 2; ++q) {
            const int c = cl + q * 16;
            const float sR = s[16 + q];
            float ls = 0.f;
#pragma unroll
            for (int hc = 0; hc < 4; ++hc) {
                const float S1 = s[q * 8 + hc];
                const float S2 = s[q * 8 + 4 + hc];
                const float mu = S1 / sR;
                float ss = S2 / sR - mu * mu;
                ss = fmaxf(ss, 1e-30f);
                const int ix = lane * 4 + q * 256 + hc;
                mu_s[ix] = mu;
                n2_s[ix] = -0.5f / ss;
                hl_s[ix] = -0.5f * __logf(ss) - HALF_LN2PI;
                ls += __logf(sqrtf(ss) + EPS);
            }
            ls += __shfl_xor(ls, 1);
            ls += __shfl_xor(ls, 2);
            const float cost = sR * (16.0f * beta_v[c] + ls);
            const float av = 1.0f / (1.0f + __expf(-lam * (beta_a[c] - cost)));
            if (hr == 0) a_s[c] = av;
        }
    }
    __syncthreads();

    const float aca = a_s[cl], acb = a_s[cl + 16];
    __align__(16) float mua[4], mub[4], na[4], nb[4], ha[4], hb[4];
    *(float4*)mua = *(const float4*)&mu_s[lane * 4];
    *(float4*)mub = *(const float4*)&mu_s[lane * 4 + 256];
    *(float4*)na  = *(const float4*)&n2_s[lane * 4];
    *(float4*)nb  = *(const float4*)&n2_s[lane * 4 + 256];
    *(float4*)ha  = *(const float4*)&hl_s[lane * 4];
    *(float4*)hb  = *(const float4*)&hl_s[lane * 4 + 256];

    const float* Wt = W + (size_t)(i0 + wave * 18) * 512 + (lane << 2);
#pragma unroll 3
    for (int t = 0; t < 18; ++t) {
        const int il = wave * 18 + t;
        const int i = i0 + il;
        const float4 wva = *(const float4*)(Wt + (size_t)t * 512);
        const float4 wvb = *(const float4*)(Wt + (size_t)t * 512 + 256);
        float pea = 0.f, peb = 0.f;
#pragma unroll
        for (int hc = 0; hc < 4; ++hc) {
            const float4 pv = *(const float4*)&Pt_lds[il * 16 + hc * 4];
            float Va = wva.x * pv.x + wva.y * pv.y + wva.z * pv.z + wva.w * pv.w;
            float Vb = wvb.x * pv.x + wvb.y * pv.y + wvb.z * pv.z + wvb.w * pv.w;
            float da = Va - mua[hc];
            float db = Vb - mub[hc];
            pea += __expf(fmaf(da * da, na[hc], ha[hc]));
            peb += __expf(fmaf(db * db, nb[hc], hb[hc]));
        }
        pea += __shfl_xor(pea, 1);
        pea += __shfl_xor(pea, 2);
        peb += __shfl_xor(peb, 1);
        peb += __shfl_xor(peb, 2);
        const float apa = aca * pea;
        const float apb = acb * peb;
        if (hr == 0) {
            ap_buf[apbase + (size_t)i * 32 + cl]      = apa;
            ap_buf[apbase + (size_t)i * 32 + cl + 16] = apb;
        }
        float dsum = apa + apb;
        dsum += __shfl_xor(dsum, 4);
        dsum += __shfl_xor(dsum, 8);
        dsum += __shfl_xor(dsum, 16);
        dsum += __shfl_xor(dsum, 32);
        if (lane == 0)
            atomicAdd(&denom_next[bb * 288 + i], dsum);
    }
}

__global__ __launch_bounds__(64)
void s_out(const float* __restrict__ Mpart, const float* __restrict__ beta_v,
           const float* __restrict__ beta_a, const float* __restrict__ lambda_p,
           float* __restrict__ d_out)
{
    const int lane = threadIdx.x;
    const int cl = lane >> 2, hr = lane & 3;
    const int blk = blockIdx.x;
    const int bb = blk / 36, p = blk - bb * 36;

    float s[18];
    const float* mp = Mpart + (size_t)blk * 4608;
#pragma unroll
    for (int k = 0; k < 18; ++k)
        s[k] = mp[k * 64 + lane] + mp[1152 + k * 64 + lane]
             + mp[2304 + k * 64 + lane] + mp[3456 + k * 64 + lane];

    const float lam = lambda_p[0];
#pragma unroll
    for (int q = 0; q < 2; ++q) {
        const int c = cl + q * 16;
        const float sR = s[16 + q];
        float ls = 0.f;
#pragma unroll
        for (int hc = 0; hc < 4; ++hc) {
            const float S1 = s[q * 8 + hc];
            const float S2 = s[q * 8 + 4 + hc];
            const float mu = S1 / sR;
            float ss = S2 / sR - mu * mu;
            ss = fmaxf(ss, 1e-30f);
            d_out[(size_t)bb * 18432 + (size_t)(c * 36 + p) * 16 + hr * 4 + hc] = mu;
            ls += __logf(sqrtf(ss) + EPS);
        }
        ls += __shfl_xor(ls, 1);
        ls += __shfl_xor(ls, 2);
        const float cost = sR * (16.0f * beta_v[c] + ls);
        const float av = 1.0f / (1.0f + __expf(-lam * (beta_a[c] - cost)));
        if (hr == 0)
            d_out[294912 + (size_t)bb * 1152 + c * 36 + p] = av;
    }
}

extern "C" void kernel_launch(void* const* d_in, const int* in_sizes, int n_in,
                              void* d_out, int out_size, void* d_ws, size_t ws_size,
                              hipStream_t stream)
{
    const float* lambda_p = (const float*)d_in[0];
    const float* poses    = (const float*)d_in[1];
    const float* acts     = (const float*)d_in[2];
    const float* W        = (const float*)d_in[3];
    const float* beta_v   = (const float*)d_in[4];
    const float* beta_a   = (const float*)d_in[5];
    float* out = (float*)d_out;

    float* ws     = (float*)d_ws;
    float* Ptg    = ws;                     // 576*4608 = 2,654,208 floats
    float* actp   = Ptg + 2654208;          // 576*288  =   165,888
    float* ap_buf = actp + 165888;          // 576*9216 = 5,308,416
    float* Mpart  = ap_buf + 5308416;       // 2304*1152 = 2,654,208
    float* denom0 = Mpart + 2654208;        // 4608
    float* denom1 = denom0 + 4608;          // 4608

    hipMemsetAsync(denom0, 0, 2 * 4608 * sizeof(float), stream);
    m_pass<0><<<2304, 256, 0, stream>>>(poses, acts, Ptg, actp, W, ap_buf, denom1, Mpart);
    e_pass<<<2304, 256, 0, stream>>>(Ptg, Mpart, W, beta_v, beta_a, lambda_p, ap_buf, denom0);
    m_pass<1><<<2304, 256, 0, stream>>>(poses, acts, Ptg, actp, W, ap_buf, denom0, Mpart);
    e_pass<<<2304, 256, 0, stream>>>(Ptg, Mpart, W, beta_v, beta_a, lambda_p, ap_buf, denom1);
    m_pass<2><<<2304, 256, 0, stream>>>(poses, acts, Ptg, actp, W, ap_buf, denom1, Mpart);
    s_out<<<576, 64, 0, stream>>>(Mpart, beta_v, beta_a, lambda_p, out);
}